// Round 1
// baseline (429.101 us; speedup 1.0000x reference)
//
#include <hip/hip_runtime.h>
#include <hip/hip_bf16.h>
#include <stdint.h>

// Problem constants (B=4, S=2048, H=1024, E=8, K=2)
#define E_    8
#define H_    1024
#define NTOK  8192           // B*S
#define KSEL  2
#define NSLOT (NTOK * KSEL)  // 16384

typedef __attribute__((ext_vector_type(8))) short   short8_t;  // 8 bf16 in 4 VGPRs
typedef __attribute__((ext_vector_type(4))) float   f32x4;

// ---- workspace layout (bytes) ----
#define CNT_OFF   0                        // 8 ints
#define CUR_OFF   64                       // 8 ints
#define OFFS_OFF  128                      // 9 ints
#define TOK_OFF   1024                     // NSLOT ints (64 KB)
#define WSL_OFF   (TOK_OFF + NSLOT * 4)    // NSLOT floats (64 KB)
#define AG_ROWS   (NSLOT + 128)            // +1 tile of padding for tail reads
#define AG_OFF    (1 << 18)                              // 256 KB
#define H1_OFF    (AG_OFF + AG_ROWS * H_ * 2)
#define W1T_OFF   (H1_OFF + AG_ROWS * H_ * 2)
#define W2T_OFF   (W1T_OFF + E_ * H_ * H_ * 2)

// GEMM tiling
#define BM 128
#define BN 128
#define BK 64

// ---------------------------------------------------------------------------
// async global->LDS, 16B per lane. LDS dst must be wave-uniform base.
__device__ __forceinline__ void async_copy16(const void* g, void* l) {
  __builtin_amdgcn_global_load_lds(
      (const __attribute__((address_space(1))) unsigned int*)g,
      (__attribute__((address_space(3))) unsigned int*)l,
      16, 0, 0);
}

// ---------------------------------------------------------------------------
__global__ void route_count(const int* __restrict__ idx, int* __restrict__ cnt) {
  int p = blockIdx.x * 256 + threadIdx.x;
  if (p < NSLOT) atomicAdd(&cnt[idx[p]], 1);
}

__global__ void route_scan(const int* __restrict__ cnt, int* __restrict__ offs,
                           int* __restrict__ cur) {
  if (threadIdx.x == 0) {
    int s = 0;
    for (int e = 0; e < E_; ++e) { offs[e] = s; cur[e] = s; s += cnt[e]; }
    offs[E_] = s;
  }
}

__global__ void route_scatter(const int* __restrict__ idx, const float* __restrict__ tkw,
                              int* __restrict__ cur, int* __restrict__ tok,
                              float* __restrict__ wsl) {
  int p = blockIdx.x * 256 + threadIdx.x;
  if (p < NSLOT) {
    int e = idx[p];
    int pos = atomicAdd(&cur[e], 1);
    tok[pos] = p >> 1;    // token id (K=2)
    wsl[pos] = tkw[p];
  }
}

// ---------------------------------------------------------------------------
// wt[e][f][h] = (bf16) w[e][h][f]   (K-contiguous layout for MFMA B fragments)
__global__ void transpose_cast(const float* __restrict__ w, __hip_bfloat16* __restrict__ wt) {
  __shared__ float t[32][33];
  const int e = blockIdx.z;
  const float* W = w + ((size_t)e << 20);
  __hip_bfloat16* WT = wt + ((size_t)e << 20);
  const int h0 = blockIdx.y * 32, f0 = blockIdx.x * 32;
  const int tx = threadIdx.x, ty = threadIdx.y;  // 32 x 8
#pragma unroll
  for (int i = 0; i < 32; i += 8)
    t[ty + i][tx] = W[(size_t)(h0 + ty + i) * H_ + f0 + tx];
  __syncthreads();
#pragma unroll
  for (int i = 0; i < 32; i += 8)
    WT[(size_t)(f0 + ty + i) * H_ + h0 + tx] = __float2bfloat16(t[tx][ty + i]);
}

// ---------------------------------------------------------------------------
// Pack routed rows: Ag[p][:] = (bf16) x[tok[p]][:]
__global__ void gather_cast(const float* __restrict__ x, const int* __restrict__ tok,
                            __hip_bfloat16* __restrict__ Ag) {
  const int p = blockIdx.x;
  const int c = threadIdx.x;  // 256 threads, 4 elems each
  const int t = tok[p];
  float4 v = ((const float4*)(x + (size_t)t * H_))[c];
  union { __hip_bfloat16 h[4]; uint2 u; } cv;
  cv.h[0] = __float2bfloat16(v.x);
  cv.h[1] = __float2bfloat16(v.y);
  cv.h[2] = __float2bfloat16(v.z);
  cv.h[3] = __float2bfloat16(v.w);
  *reinterpret_cast<uint2*>(Ag + (size_t)p * H_ + (size_t)c * 4) = cv.u;
}

// ---------------------------------------------------------------------------
// Grouped GEMM.  EPI=0: h1 = relu(A @ W^T + b)  -> bf16
//               EPI=1: out[tok[p]] += wsl[p] * (A @ W^T + b)   (f32 atomics)
template <int EPI>
__launch_bounds__(256, 2)
__global__ void moe_gemm(const __hip_bfloat16* __restrict__ Abase,
                         const __hip_bfloat16* __restrict__ Wt,   // [E][H][H] (f-major)
                         const float* __restrict__ bias,          // [E][H]
                         __hip_bfloat16* __restrict__ h1out,
                         float* __restrict__ out,
                         const int* __restrict__ cnt, const int* __restrict__ offs,
                         const int* __restrict__ tok, const float* __restrict__ wsl) {
  const int e = blockIdx.z;
  const int count = cnt[e];
  const int mt = blockIdx.y;
  if (mt * BM >= count) return;

  const int tid = threadIdx.x;
  const int wid = tid >> 6, lane = tid & 63;
  const int wm = wid >> 1, wn = wid & 1;  // 2x2 waves -> 64x64 each

  const size_t Arow0 = (size_t)(offs[e] + mt * BM);
  const __hip_bfloat16* Aexp = Abase + Arow0 * H_;
  const __hip_bfloat16* Bexp = Wt + ((size_t)e * H_ * H_) + (size_t)(blockIdx.x * BN) * H_;

  __shared__ __hip_bfloat16 smA[2][BM * BK];  // 16 KB each
  __shared__ __hip_bfloat16 smB[2][BN * BK];  // total 64 KB

  const int srow = lane >> 3;          // 0..7 within 8-row chunk
  const int scol = (lane & 7) * 8;     // elem offset within row (8 bf16 = 16B)

  f32x4 acc[4][4];
#pragma unroll
  for (int m = 0; m < 4; ++m)
#pragma unroll
    for (int n = 0; n < 4; ++n) acc[m][n] = f32x4{0.f, 0.f, 0.f, 0.f};

  auto stage = [&](int s, int kt) {
#pragma unroll
    for (int i = 0; i < 4; ++i) {
      const int c = i * 4 + wid;  // chunk 0..15 (8 rows x 1KB)
      async_copy16(Aexp + (size_t)(c * 8 + srow) * H_ + kt * BK + scol, &smA[s][c * 512]);
    }
#pragma unroll
    for (int i = 0; i < 4; ++i) {
      const int c = i * 4 + wid;
      async_copy16(Bexp + (size_t)(c * 8 + srow) * H_ + kt * BK + scol, &smB[s][c * 512]);
    }
  };

  stage(0, 0);
  __syncthreads();

  int cur = 0;
  const int KT = H_ / BK;  // 16
  for (int kt = 0; kt < KT; ++kt) {
    if (kt + 1 < KT) stage(cur ^ 1, kt + 1);
#pragma unroll
    for (int ks = 0; ks < 2; ++ks) {
      short8_t a[4], b[4];
#pragma unroll
      for (int m = 0; m < 4; ++m)
        a[m] = *(const short8_t*)&smA[cur][(wm * 64 + m * 16 + (lane & 15)) * BK + ks * 32 + (lane >> 4) * 8];
#pragma unroll
      for (int n = 0; n < 4; ++n)
        b[n] = *(const short8_t*)&smB[cur][(wn * 64 + n * 16 + (lane & 15)) * BK + ks * 32 + (lane >> 4) * 8];
#pragma unroll
      for (int m = 0; m < 4; ++m)
#pragma unroll
        for (int n = 0; n < 4; ++n)
          acc[m][n] = __builtin_amdgcn_mfma_f32_16x16x32_bf16(a[m], b[n], acc[m][n], 0, 0, 0);
    }
    __syncthreads();
    cur ^= 1;
  }

  const int colb = blockIdx.x * BN + wn * 64;
  if constexpr (EPI == 0) {
#pragma unroll
    for (int n = 0; n < 4; ++n) {
      const int col = colb + n * 16 + (lane & 15);
      const float bv = bias[e * H_ + col];
#pragma unroll
      for (int m = 0; m < 4; ++m)
#pragma unroll
        for (int r = 0; r < 4; ++r) {
          const int lr = wm * 64 + m * 16 + (lane >> 4) * 4 + r;
          if (mt * BM + lr < count) {
            float v = acc[m][n][r] + bv;
            h1out[(Arow0 + lr) * H_ + col] = __float2bfloat16(fmaxf(v, 0.f));
          }
        }
    }
  } else {
#pragma unroll
    for (int m = 0; m < 4; ++m)
#pragma unroll
      for (int r = 0; r < 4; ++r) {
        const int lr = wm * 64 + m * 16 + (lane >> 4) * 4 + r;
        if (mt * BM + lr < count) {
          const int p = (int)Arow0 + lr;
          const int t = tok[p];
          const float w = wsl[p];
#pragma unroll
          for (int n = 0; n < 4; ++n) {
            const int col = colb + n * 16 + (lane & 15);
            float v = (acc[m][n][r] + bias[e * H_ + col]) * w;
            atomicAdd(out + (size_t)t * H_ + col, v);
          }
        }
      }
  }
}

// ---------------------------------------------------------------------------
extern "C" void kernel_launch(void* const* d_in, const int* in_sizes, int n_in,
                              void* d_out, int out_size, void* d_ws, size_t ws_size,
                              hipStream_t stream) {
  const float* x   = (const float*)d_in[0];
  const int*   idx = (const int*)d_in[1];
  const float* tkw = (const float*)d_in[2];
  const float* w1  = (const float*)d_in[3];
  const float* b1  = (const float*)d_in[4];
  const float* w2  = (const float*)d_in[5];
  const float* b2  = (const float*)d_in[6];
  float* out = (float*)d_out;

  uint8_t* ws = (uint8_t*)d_ws;
  int*   cnt  = (int*)(ws + CNT_OFF);
  int*   cur  = (int*)(ws + CUR_OFF);
  int*   offs = (int*)(ws + OFFS_OFF);
  int*   tok  = (int*)(ws + TOK_OFF);
  float* wsl  = (float*)(ws + WSL_OFF);
  __hip_bfloat16* Ag  = (__hip_bfloat16*)(ws + AG_OFF);
  __hip_bfloat16* h1  = (__hip_bfloat16*)(ws + H1_OFF);
  __hip_bfloat16* w1t = (__hip_bfloat16*)(ws + W1T_OFF);
  __hip_bfloat16* w2t = (__hip_bfloat16*)(ws + W2T_OFF);

  hipMemsetAsync(ws, 0, 1024, stream);                                // counters
  hipMemsetAsync(d_out, 0, (size_t)out_size * sizeof(float), stream); // output accum

  transpose_cast<<<dim3(H_ / 32, H_ / 32, E_), dim3(32, 8), 0, stream>>>(w1, w1t);
  transpose_cast<<<dim3(H_ / 32, H_ / 32, E_), dim3(32, 8), 0, stream>>>(w2, w2t);

  route_count<<<NSLOT / 256, 256, 0, stream>>>(idx, cnt);
  route_scan<<<1, 64, 0, stream>>>(cnt, offs, cur);
  route_scatter<<<NSLOT / 256, 256, 0, stream>>>(idx, tkw, cur, tok, wsl);
  gather_cast<<<NSLOT, 256, 0, stream>>>(x, tok, Ag);

  moe_gemm<0><<<dim3(H_ / BN, NSLOT / BM, E_), 256, 0, stream>>>(
      Ag, w1t, b1, h1, nullptr, cnt, offs, tok, wsl);
  moe_gemm<1><<<dim3(H_ / BN, NSLOT / BM, E_), 256, 0, stream>>>(
      h1, w2t, b2, nullptr, out, cnt, offs, tok, wsl);
}

// Round 2
// 363.655 us; speedup vs baseline: 1.1800x; 1.1800x over previous
//
#include <hip/hip_runtime.h>
#include <hip/hip_bf16.h>
#include <stdint.h>

// Problem constants (B=4, S=2048, H=1024, E=8, K=2)
#define E_    8
#define H_    1024
#define NTOK  8192           // B*S
#define KSEL  2
#define NSLOT (NTOK * KSEL)  // 16384

typedef __attribute__((ext_vector_type(8))) short   short8_t;  // 8 bf16 in 4 VGPRs
typedef __attribute__((ext_vector_type(4))) float   f32x4;

// ---- workspace layout (bytes) ----
#define CNT_OFF   0                        // 8 ints
#define CUR_OFF   64                       // 8 ints
#define OFFS_OFF  128                      // 9 ints
#define TOK_OFF   1024                     // NSLOT ints (64 KB)
#define WSL_OFF   (TOK_OFF + NSLOT * 4)    // NSLOT floats (64 KB)
#define AG_ROWS   (NSLOT + 128)            // +1 tile of padding for tail reads
#define AG_OFF    (1 << 18)                              // 256 KB
#define H1_OFF    (AG_OFF + AG_ROWS * H_ * 2)
#define W1T_OFF   (H1_OFF + AG_ROWS * H_ * 2)
#define W2T_OFF   (W1T_OFF + E_ * H_ * H_ * 2)

// GEMM tiling
#define BM 128
#define BN 128
#define BK 64

// ---------------------------------------------------------------------------
// async global->LDS, 16B per lane. LDS dst must be wave-uniform base.
__device__ __forceinline__ void async_copy16(const void* g, void* l) {
  __builtin_amdgcn_global_load_lds(
      (const __attribute__((address_space(1))) unsigned int*)g,
      (__attribute__((address_space(3))) unsigned int*)l,
      16, 0, 0);
}

// ---------------------------------------------------------------------------
__global__ void route_count(const int* __restrict__ idx, int* __restrict__ cnt) {
  int p = blockIdx.x * 256 + threadIdx.x;
  if (p < NSLOT) atomicAdd(&cnt[idx[p]], 1);
}

__global__ void route_scan(const int* __restrict__ cnt, int* __restrict__ offs,
                           int* __restrict__ cur) {
  if (threadIdx.x == 0) {
    int s = 0;
    for (int e = 0; e < E_; ++e) { offs[e] = s; cur[e] = s; s += cnt[e]; }
    offs[E_] = s;
  }
}

__global__ void route_scatter(const int* __restrict__ idx, const float* __restrict__ tkw,
                              int* __restrict__ cur, int* __restrict__ tok,
                              float* __restrict__ wsl) {
  int p = blockIdx.x * 256 + threadIdx.x;
  if (p < NSLOT) {
    int e = idx[p];
    int pos = atomicAdd(&cur[e], 1);
    tok[pos] = p >> 1;    // token id (K=2)
    wsl[pos] = tkw[p];
  }
}

// ---------------------------------------------------------------------------
// wt[e][f][h] = (bf16) w[e][h][f]   (K-contiguous layout for MFMA B fragments)
__global__ void transpose_cast(const float* __restrict__ w, __hip_bfloat16* __restrict__ wt) {
  __shared__ float t[32][33];
  const int e = blockIdx.z;
  const float* W = w + ((size_t)e << 20);
  __hip_bfloat16* WT = wt + ((size_t)e << 20);
  const int h0 = blockIdx.y * 32, f0 = blockIdx.x * 32;
  const int tx = threadIdx.x, ty = threadIdx.y;  // 32 x 8
#pragma unroll
  for (int i = 0; i < 32; i += 8)
    t[ty + i][tx] = W[(size_t)(h0 + ty + i) * H_ + f0 + tx];
  __syncthreads();
#pragma unroll
  for (int i = 0; i < 32; i += 8)
    WT[(size_t)(f0 + ty + i) * H_ + h0 + tx] = __float2bfloat16(t[tx][ty + i]);
}

// ---------------------------------------------------------------------------
// Pack routed rows: Ag[p][:] = (bf16) x[tok[p]][:]
__global__ void gather_cast(const float* __restrict__ x, const int* __restrict__ tok,
                            __hip_bfloat16* __restrict__ Ag) {
  const int p = blockIdx.x;
  const int c = threadIdx.x;  // 256 threads, 4 elems each
  const int t = tok[p];
  float4 v = ((const float4*)(x + (size_t)t * H_))[c];
  union { __hip_bfloat16 h[4]; uint2 u; } cv;
  cv.h[0] = __float2bfloat16(v.x);
  cv.h[1] = __float2bfloat16(v.y);
  cv.h[2] = __float2bfloat16(v.z);
  cv.h[3] = __float2bfloat16(v.w);
  *reinterpret_cast<uint2*>(Ag + (size_t)p * H_ + (size_t)c * 4) = cv.u;
}

// ---------------------------------------------------------------------------
// Grouped GEMM (m97 structure: SINGLE 32KB LDS buffer, 2-barrier K-loop,
// latency hidden by block-level TLP at ~5 blocks/CU).
//   EPI=0: h1 = relu(A @ W^T + b)  -> bf16
//   EPI=1: out[tok[p]] += wsl[p] * (A @ W^T + b)   (f32 atomics)
template <int EPI>
__launch_bounds__(256, 4)
__global__ void moe_gemm(const __hip_bfloat16* __restrict__ Abase,
                         const __hip_bfloat16* __restrict__ Wt,   // [E][H][H] (f-major)
                         const float* __restrict__ bias,          // [E][H]
                         __hip_bfloat16* __restrict__ h1out,
                         float* __restrict__ out,
                         const int* __restrict__ cnt, const int* __restrict__ offs,
                         const int* __restrict__ tok, const float* __restrict__ wsl) {
  const int e = blockIdx.z;
  const int count = cnt[e];
  const int mt = blockIdx.y;
  if (mt * BM >= count) return;

  const int tid = threadIdx.x;
  const int wid = tid >> 6, lane = tid & 63;
  const int wm = wid >> 1, wn = wid & 1;  // 2x2 waves -> 64x64 each

  const size_t Arow0 = (size_t)(offs[e] + mt * BM);
  const __hip_bfloat16* Aexp = Abase + Arow0 * H_;
  const __hip_bfloat16* Bexp = Wt + ((size_t)e * H_ * H_) + (size_t)(blockIdx.x * BN) * H_;

  __shared__ __hip_bfloat16 smA[BM * BK];  // 16 KB
  __shared__ __hip_bfloat16 smB[BN * BK];  // 16 KB  (32 KB total -> 5 blocks/CU)

  const int srow = lane >> 3;          // 0..7 within 8-row chunk
  const int scol = (lane & 7) * 8;     // elem offset within row (8 bf16 = 16B)

  f32x4 acc[4][4];
#pragma unroll
  for (int m = 0; m < 4; ++m)
#pragma unroll
    for (int n = 0; n < 4; ++n) acc[m][n] = f32x4{0.f, 0.f, 0.f, 0.f};

  auto stage = [&](int kt) {
#pragma unroll
    for (int i = 0; i < 4; ++i) {
      const int c = i * 4 + wid;  // chunk 0..15 (8 rows x 1KB)
      async_copy16(Aexp + (size_t)(c * 8 + srow) * H_ + kt * BK + scol, &smA[c * 512]);
    }
#pragma unroll
    for (int i = 0; i < 4; ++i) {
      const int c = i * 4 + wid;
      async_copy16(Bexp + (size_t)(c * 8 + srow) * H_ + kt * BK + scol, &smB[c * 512]);
    }
  };

  const int KT = H_ / BK;  // 16
  for (int kt = 0; kt < KT; ++kt) {
    stage(kt);
    __syncthreads();  // compiler emits vmcnt(0) drain; hidden by co-resident blocks
#pragma unroll
    for (int ks = 0; ks < 2; ++ks) {
      short8_t a[4], b[4];
#pragma unroll
      for (int m = 0; m < 4; ++m)
        a[m] = *(const short8_t*)&smA[(wm * 64 + m * 16 + (lane & 15)) * BK + ks * 32 + (lane >> 4) * 8];
#pragma unroll
      for (int n = 0; n < 4; ++n)
        b[n] = *(const short8_t*)&smB[(wn * 64 + n * 16 + (lane & 15)) * BK + ks * 32 + (lane >> 4) * 8];
#pragma unroll
      for (int m = 0; m < 4; ++m)
#pragma unroll
        for (int n = 0; n < 4; ++n)
          acc[m][n] = __builtin_amdgcn_mfma_f32_16x16x32_bf16(a[m], b[n], acc[m][n], 0, 0, 0);
    }
    __syncthreads();  // protect LDS before next stage overwrites
  }

  const int colb = blockIdx.x * BN + wn * 64;
  if constexpr (EPI == 0) {
#pragma unroll
    for (int n = 0; n < 4; ++n) {
      const int col = colb + n * 16 + (lane & 15);
      const float bv = bias[e * H_ + col];
#pragma unroll
      for (int m = 0; m < 4; ++m)
#pragma unroll
        for (int r = 0; r < 4; ++r) {
          const int lr = wm * 64 + m * 16 + (lane >> 4) * 4 + r;
          if (mt * BM + lr < count) {
            float v = acc[m][n][r] + bv;
            h1out[(Arow0 + lr) * H_ + col] = __float2bfloat16(fmaxf(v, 0.f));
          }
        }
    }
  } else {
#pragma unroll
    for (int m = 0; m < 4; ++m)
#pragma unroll
      for (int r = 0; r < 4; ++r) {
        const int lr = wm * 64 + m * 16 + (lane >> 4) * 4 + r;
        if (mt * BM + lr < count) {
          const int p = (int)Arow0 + lr;
          const int t = tok[p];
          const float w = wsl[p];
#pragma unroll
          for (int n = 0; n < 4; ++n) {
            const int col = colb + n * 16 + (lane & 15);
            float v = (acc[m][n][r] + bias[e * H_ + col]) * w;
            atomicAdd(out + (size_t)t * H_ + col, v);
          }
        }
      }
  }
}

// ---------------------------------------------------------------------------
extern "C" void kernel_launch(void* const* d_in, const int* in_sizes, int n_in,
                              void* d_out, int out_size, void* d_ws, size_t ws_size,
                              hipStream_t stream) {
  const float* x   = (const float*)d_in[0];
  const int*   idx = (const int*)d_in[1];
  const float* tkw = (const float*)d_in[2];
  const float* w1  = (const float*)d_in[3];
  const float* b1  = (const float*)d_in[4];
  const float* w2  = (const float*)d_in[5];
  const float* b2  = (const float*)d_in[6];
  float* out = (float*)d_out;

  uint8_t* ws = (uint8_t*)d_ws;
  int*   cnt  = (int*)(ws + CNT_OFF);
  int*   cur  = (int*)(ws + CUR_OFF);
  int*   offs = (int*)(ws + OFFS_OFF);
  int*   tok  = (int*)(ws + TOK_OFF);
  float* wsl  = (float*)(ws + WSL_OFF);
  __hip_bfloat16* Ag  = (__hip_bfloat16*)(ws + AG_OFF);
  __hip_bfloat16* h1  = (__hip_bfloat16*)(ws + H1_OFF);
  __hip_bfloat16* w1t = (__hip_bfloat16*)(ws + W1T_OFF);
  __hip_bfloat16* w2t = (__hip_bfloat16*)(ws + W2T_OFF);

  hipMemsetAsync(ws, 0, 1024, stream);                                // counters
  hipMemsetAsync(d_out, 0, (size_t)out_size * sizeof(float), stream); // output accum

  transpose_cast<<<dim3(H_ / 32, H_ / 32, E_), dim3(32, 8), 0, stream>>>(w1, w1t);
  transpose_cast<<<dim3(H_ / 32, H_ / 32, E_), dim3(32, 8), 0, stream>>>(w2, w2t);

  route_count<<<NSLOT / 256, 256, 0, stream>>>(idx, cnt);
  route_scan<<<1, 64, 0, stream>>>(cnt, offs, cur);
  route_scatter<<<NSLOT / 256, 256, 0, stream>>>(idx, tkw, cur, tok, wsl);
  gather_cast<<<NSLOT, 256, 0, stream>>>(x, tok, Ag);

  moe_gemm<0><<<dim3(H_ / BN, NSLOT / BM, E_), 256, 0, stream>>>(
      Ag, w1t, b1, h1, nullptr, cnt, offs, tok, wsl);
  moe_gemm<1><<<dim3(H_ / BN, NSLOT / BM, E_), 256, 0, stream>>>(
      h1, w2t, b2, nullptr, out, cnt, offs, tok, wsl);
}